// Round 3
// baseline (1414.122 us; speedup 1.0000x reference)
//
#include <hip/hip_runtime.h>

#define B_ 2
#define S_ 2048
#define D_ 2048
#define H_ 16
#define DH_ 128
#define FF_ 5632
#define M_ (B_*S_)   // 4096 token rows

typedef unsigned short u16;
typedef unsigned int u32;
typedef __attribute__((ext_vector_type(8))) short short8;   // 8 bf16 (4 VGPRs)
typedef __attribute__((ext_vector_type(4))) float floatx4;  // MFMA C/D

__device__ __forceinline__ float bf2f(u16 h) {
  union { u32 u; float f; } v; v.u = ((u32)h) << 16; return v.f;
}
__device__ __forceinline__ u16 f2bf(float f) {
  union { float f; u32 u; } v; v.f = f;
  u32 u = v.u;
  return (u16)((u + 0x7FFFu + ((u >> 16) & 1u)) >> 16);
}
// dtype probe: freqs_cos[0] is cos(0)=1.0. f32 -> word0 = 0x3F800000 (low16==0),
// bf16 -> word0 = 0x3F803F80 (low16==0x3F80).
__device__ __forceinline__ bool probe_f32(const u32* p) { return (p[0] & 0xFFFFu) == 0u; }

// ---------------- RMSNorm: one block per row of 2048 ----------------
__global__ __launch_bounds__(256) void rmsnorm_kernel(
    const void* __restrict__ x, const void* __restrict__ w, u16* __restrict__ o,
    const u32* __restrict__ probe, int x_ext) {
  const bool m = probe_f32(probe);
  const bool xf = m && (x_ext != 0);
  const int row = blockIdx.x;
  const int tid = threadIdx.x;
  float v[8];
  if (xf) {
    const float* xr = (const float*)x + (size_t)row * D_;
    float4 p0 = *(const float4*)(xr + tid * 8);
    float4 p1 = *(const float4*)(xr + tid * 8 + 4);
    v[0]=p0.x; v[1]=p0.y; v[2]=p0.z; v[3]=p0.w;
    v[4]=p1.x; v[5]=p1.y; v[6]=p1.z; v[7]=p1.w;
  } else {
    const u16* xr = (const u16*)x + (size_t)row * D_;
    uint4 p = *(const uint4*)(xr + tid * 8);
    u32 ua[4] = {p.x, p.y, p.z, p.w};
#pragma unroll
    for (int i = 0; i < 4; ++i) {
      v[2*i]   = bf2f((u16)(ua[i] & 0xffffu));
      v[2*i+1] = bf2f((u16)(ua[i] >> 16));
    }
  }
  float ss = 0.f;
#pragma unroll
  for (int i = 0; i < 8; ++i) ss += v[i] * v[i];
#pragma unroll
  for (int d = 1; d < 64; d <<= 1) ss += __shfl_xor(ss, d);
  __shared__ float sbuf[4];
  if ((tid & 63) == 0) sbuf[tid >> 6] = ss;
  __syncthreads();
  float tot = sbuf[0] + sbuf[1] + sbuf[2] + sbuf[3];
  float sc = rsqrtf(tot * (1.0f / (float)D_) + 1e-6f);
  float wv[8];
  if (m) {
    const float* wr = (const float*)w;
    float4 p0 = *(const float4*)(wr + tid * 8);
    float4 p1 = *(const float4*)(wr + tid * 8 + 4);
    wv[0]=p0.x; wv[1]=p0.y; wv[2]=p0.z; wv[3]=p0.w;
    wv[4]=p1.x; wv[5]=p1.y; wv[6]=p1.z; wv[7]=p1.w;
  } else {
    uint4 pw = *(const uint4*)((const u16*)w + tid * 8);
    u32 uw[4] = {pw.x, pw.y, pw.z, pw.w};
#pragma unroll
    for (int i = 0; i < 4; ++i) {
      wv[2*i]   = bf2f((u16)(uw[i] & 0xffffu));
      wv[2*i+1] = bf2f((u16)(uw[i] >> 16));
    }
  }
  u32 ow[4];
#pragma unroll
  for (int i = 0; i < 4; ++i) {
    float n0 = v[2*i] * sc, n1 = v[2*i+1] * sc;
    if (!m) { n0 = bf2f(f2bf(n0)); n1 = bf2f(f2bf(n1)); }  // match n.astype(bf16) in bf16 world
    n0 *= wv[2*i]; n1 *= wv[2*i+1];
    ow[i] = (u32)f2bf(n0) | ((u32)f2bf(n1) << 16);
  }
  uint4 po; po.x = ow[0]; po.y = ow[1]; po.z = ow[2]; po.w = ow[3];
  *(uint4*)(o + (size_t)row * D_ + tid * 8) = po;
}

// ---------------- GEMM: C[M,N] = A[M,K] @ B[K,N], bf16 MFMA ----------------
// block = 256 thr (4 waves), tile 128x128, BK=32, wave tile 64x64 (4x4 mfma frags)
// EPI: 0 plain | 1 C=acc+Res | 2 C=silu(acc) | 3 C=acc*Res (Res aliases C, both internal)
// A is ALWAYS internal bf16. B is ALWAYS an external weight (dual dtype).
// NOTE: no __restrict__ on C/Res — they alias for EPI==3.
template<int EPI>
__global__ __launch_bounds__(256, 2) void gemm_kernel(
    const u16* __restrict__ A, const void* __restrict__ Bm,
    void* C, const void* Res,
    int Ndim, int Kdim, const u32* __restrict__ probe, int res_ext, int c_ext) {
  const bool m = probe_f32(probe);
  const bool rf = m && (res_ext != 0);
  const bool cf = m && (c_ext != 0);
  __shared__ u16 As[128][40];  // [m][k], +8 pad
  __shared__ u16 Bs[128][40];  // [n][k] (B transposed on stage)
  const int tid = threadIdx.x;
  const int wave = tid >> 6, lane = tid & 63;
  const int quad = lane >> 4, l16 = lane & 15;
  const int waveM = wave & 1, waveN = wave >> 1;
  const int mb = blockIdx.y * 128, nb = blockIdx.x * 128;

  floatx4 acc[4][4];
#pragma unroll
  for (int i = 0; i < 4; ++i)
#pragma unroll
    for (int j = 0; j < 4; ++j) { floatx4 z = {0.f,0.f,0.f,0.f}; acc[i][j] = z; }

  const int kTiles = Kdim >> 5;
  for (int kt = 0; kt < kTiles; ++kt) {
    const int k0 = kt << 5;
#pragma unroll
    for (int i = 0; i < 2; ++i) {
      int c = tid + i * 256;
      int row = c >> 2, kc = (c & 3) << 3;
      uint4 val = *(const uint4*)(A + (size_t)(mb + row) * Kdim + k0 + kc);
      *(uint4*)&As[row][kc] = val;
    }
    {
      int n = tid & 127, kh = tid >> 7;
      u16 t[16];
      if (m) {
        const float* Bf = (const float*)Bm;
#pragma unroll
        for (int j = 0; j < 16; ++j)
          t[j] = f2bf(Bf[(size_t)(k0 + kh * 16 + j) * Ndim + nb + n]);
      } else {
        const u16* Bh = (const u16*)Bm;
#pragma unroll
        for (int j = 0; j < 16; ++j)
          t[j] = Bh[(size_t)(k0 + kh * 16 + j) * Ndim + nb + n];
      }
      uint4 w0, w1;
      w0.x = (u32)t[0] | ((u32)t[1] << 16);   w0.y = (u32)t[2] | ((u32)t[3] << 16);
      w0.z = (u32)t[4] | ((u32)t[5] << 16);   w0.w = (u32)t[6] | ((u32)t[7] << 16);
      w1.x = (u32)t[8] | ((u32)t[9] << 16);   w1.y = (u32)t[10] | ((u32)t[11] << 16);
      w1.z = (u32)t[12] | ((u32)t[13] << 16); w1.w = (u32)t[14] | ((u32)t[15] << 16);
      *(uint4*)&Bs[n][kh * 16]     = w0;
      *(uint4*)&Bs[n][kh * 16 + 8] = w1;
    }
    __syncthreads();
    short8 af[4], bfr[4];
#pragma unroll
    for (int i = 0; i < 4; ++i)
      af[i] = *(const short8*)&As[waveM * 64 + i * 16 + l16][quad * 8];
#pragma unroll
    for (int i = 0; i < 4; ++i)
      bfr[i] = *(const short8*)&Bs[waveN * 64 + i * 16 + l16][quad * 8];
#pragma unroll
    for (int mi = 0; mi < 4; ++mi)
#pragma unroll
      for (int ni = 0; ni < 4; ++ni)
        acc[mi][ni] = __builtin_amdgcn_mfma_f32_16x16x32_bf16(af[mi], bfr[ni], acc[mi][ni], 0, 0, 0);
    __syncthreads();
  }
  // epilogue: D layout row = quad*4+r, col = l16
#pragma unroll
  for (int mi = 0; mi < 4; ++mi)
#pragma unroll
    for (int ni = 0; ni < 4; ++ni) {
      int gm0 = mb + waveM * 64 + mi * 16 + quad * 4;
      int gn  = nb + waveN * 64 + ni * 16 + l16;
#pragma unroll
      for (int r = 0; r < 4; ++r) {
        float v = acc[mi][ni][r];
        size_t idx = (size_t)(gm0 + r) * Ndim + gn;
        if (EPI == 1) v += rf ? ((const float*)Res)[idx] : bf2f(((const u16*)Res)[idx]);
        if (EPI == 2) v = v / (1.f + __expf(-v));            // silu
        if (EPI == 3) v *= bf2f(((const u16*)Res)[idx]);     // Res internal bf16, aliases C
        if (cf) ((float*)C)[idx] = v;
        else    ((u16*)C)[idx] = f2bf(v);
      }
    }
}

// ---------------- RoPE on q and k in-place ----------------
__global__ __launch_bounds__(256) void rope_kernel(
    u16* __restrict__ q, u16* __restrict__ k,
    const void* __restrict__ ct, const void* __restrict__ st,
    const u32* __restrict__ probe) {
  const bool m = probe_f32(probe);
  int idx = blockIdx.x * 256 + threadIdx.x;   // [row(4096)][h(16)][j(64)]
  int row = idx >> 10;
  int rem = idx & 1023;
  int h = rem >> 6, j = rem & 63;
  int s = row & (S_ - 1);
  size_t a = (size_t)row * D_ + h * DH_ + 2 * j;
  float c, sn;
  if (m) { c = ((const float*)ct)[s * 64 + j]; sn = ((const float*)st)[s * 64 + j]; }
  else   { c = bf2f(((const u16*)ct)[s * 64 + j]); sn = bf2f(((const u16*)st)[s * 64 + j]); }
  u32 qq = *(u32*)(q + a);
  float xr = bf2f((u16)(qq & 0xffffu)), xi = bf2f((u16)(qq >> 16));
  *(u32*)(q + a) = (u32)f2bf(xr * c - xi * sn) | ((u32)f2bf(xr * sn + xi * c) << 16);
  u32 kk = *(u32*)(k + a);
  xr = bf2f((u16)(kk & 0xffffu)); xi = bf2f((u16)(kk >> 16));
  *(u32*)(k + a) = (u32)f2bf(xr * c - xi * sn) | ((u32)f2bf(xr * sn + xi * c) << 16);
}

// ---------------- V transpose: (b,s,h,d) -> (b,h,d,s) ----------------
__global__ __launch_bounds__(256) void vtrans_kernel(
    const u16* __restrict__ v, u16* __restrict__ vt) {
  __shared__ u16 tl[64][72];
  int s0 = blockIdx.x * 64, d0 = blockIdx.y * 64;
  int bh = blockIdx.z, b = bh >> 4, h = bh & 15;
  int tid = threadIdx.x;
#pragma unroll
  for (int i = 0; i < 2; ++i) {
    int c = tid + i * 256;
    int row = c >> 3, dc = (c & 7) << 3;
    uint4 val = *(const uint4*)(v + (size_t)(b * S_ + s0 + row) * D_ + h * DH_ + d0 + dc);
    *(uint4*)&tl[row][dc] = val;
  }
  __syncthreads();
#pragma unroll
  for (int i = 0; i < 2; ++i) {
    int c = tid + i * 256;
    int dr = c >> 3, sc = (c & 7) << 3;
    u16 t[8];
#pragma unroll
    for (int j = 0; j < 8; ++j) t[j] = tl[sc + j][dr];
    uint4 w0;
    w0.x = (u32)t[0] | ((u32)t[1] << 16); w0.y = (u32)t[2] | ((u32)t[3] << 16);
    w0.z = (u32)t[4] | ((u32)t[5] << 16); w0.w = (u32)t[6] | ((u32)t[7] << 16);
    *(uint4*)(vt + (size_t)(bh * DH_ + d0 + dr) * S_ + s0 + sc) = w0;
  }
}

// ---------------- Flash attention (causal), Q-tile 128, K-tile 64 ----------------
__global__ __launch_bounds__(256, 1) void attn_kernel(
    const u16* __restrict__ q, const u16* __restrict__ k,
    const u16* __restrict__ vt, u16* __restrict__ o) {
  __shared__ u16 Ks[64][136];     // [sk][d]
  __shared__ u16 Vs[128][72];     // [d][sk]
  __shared__ u16 Ps[4][32][72];   // per-wave P round-trip [q][sk]
  const int qt = blockIdx.x, bh = blockIdx.y;
  const int b = bh >> 4, h = bh & 15;
  const int tid = threadIdx.x;
  const int wave = tid >> 6, lane = tid & 63;
  const int quad = lane >> 4, l16 = lane & 15;

  short8 qa[2][4];
  const u16* qbase = q + (size_t)(b * S_ + qt * 128 + wave * 32) * D_ + h * DH_;
#pragma unroll
  for (int mi = 0; mi < 2; ++mi)
#pragma unroll
    for (int ks = 0; ks < 4; ++ks)
      qa[mi][ks] = *(const short8*)(qbase + (size_t)(mi * 16 + l16) * D_ + ks * 32 + quad * 8);

  float m_i[2][4], l_i[2][4];
  floatx4 acc_o[2][8];
#pragma unroll
  for (int mi = 0; mi < 2; ++mi) {
#pragma unroll
    for (int r = 0; r < 4; ++r) { m_i[mi][r] = -1e30f; l_i[mi][r] = 0.f; }
#pragma unroll
    for (int nd = 0; nd < 8; ++nd) { floatx4 z = {0.f,0.f,0.f,0.f}; acc_o[mi][nd] = z; }
  }

  const int nkt = 2 * qt + 2;
  for (int kt = 0; kt < nkt; ++kt) {
#pragma unroll
    for (int i = 0; i < 4; ++i) {
      int c = tid + i * 256;
      int row = c >> 4, dc = (c & 15) << 3;
      uint4 val = *(const uint4*)(k + (size_t)(b * S_ + kt * 64 + row) * D_ + h * DH_ + dc);
      *(uint4*)&Ks[row][dc] = val;
    }
#pragma unroll
    for (int i = 0; i < 4; ++i) {
      int c = tid + i * 256;
      int row = c >> 3, sc = (c & 7) << 3;
      uint4 val = *(const uint4*)(vt + (size_t)(bh * DH_ + row) * S_ + kt * 64 + sc);
      *(uint4*)&Vs[row][sc] = val;
    }
    __syncthreads();

    floatx4 accs[2][4];
#pragma unroll
    for (int mi = 0; mi < 2; ++mi)
#pragma unroll
      for (int ni = 0; ni < 4; ++ni) { floatx4 z = {0.f,0.f,0.f,0.f}; accs[mi][ni] = z; }
#pragma unroll
    for (int ks = 0; ks < 4; ++ks) {
      short8 kf[4];
#pragma unroll
      for (int ni = 0; ni < 4; ++ni)
        kf[ni] = *(const short8*)&Ks[ni * 16 + l16][ks * 32 + quad * 8];
#pragma unroll
      for (int mi = 0; mi < 2; ++mi)
#pragma unroll
        for (int ni = 0; ni < 4; ++ni)
          accs[mi][ni] = __builtin_amdgcn_mfma_f32_16x16x32_bf16(qa[mi][ks], kf[ni], accs[mi][ni], 0, 0, 0);
    }

    const float scl = 0.08838834764831845f;  // 1/sqrt(128)
    const bool diag = (kt >= 2 * qt);
#pragma unroll
    for (int mi = 0; mi < 2; ++mi) {
#pragma unroll
      for (int r = 0; r < 4; ++r) {
        int qg = qt * 128 + wave * 32 + mi * 16 + quad * 4 + r;
        float mx = -1e30f;
#pragma unroll
        for (int ni = 0; ni < 4; ++ni) {
          float sv = accs[mi][ni][r] * scl;
          int kg = kt * 64 + ni * 16 + l16;
          if (diag && kg > qg) sv = -1e30f;
          accs[mi][ni][r] = sv;
          mx = fmaxf(mx, sv);
        }
#pragma unroll
        for (int d = 1; d < 16; d <<= 1) mx = fmaxf(mx, __shfl_xor(mx, d));
        float mn = fmaxf(m_i[mi][r], mx);
        float al = __expf(m_i[mi][r] - mn);
        float rs = 0.f;
#pragma unroll
        for (int ni = 0; ni < 4; ++ni) {
          float p = __expf(accs[mi][ni][r] - mn);
          accs[mi][ni][r] = p;
          rs += p;
        }
#pragma unroll
        for (int d = 1; d < 16; d <<= 1) rs += __shfl_xor(rs, d);
        l_i[mi][r] = l_i[mi][r] * al + rs;
        m_i[mi][r] = mn;
#pragma unroll
        for (int nd = 0; nd < 8; ++nd) acc_o[mi][nd][r] *= al;
      }
    }
#pragma unroll
    for (int mi = 0; mi < 2; ++mi)
#pragma unroll
      for (int ni = 0; ni < 4; ++ni)
#pragma unroll
        for (int r = 0; r < 4; ++r)
          Ps[wave][mi * 16 + quad * 4 + r][ni * 16 + l16] = f2bf(accs[mi][ni][r]);
    __syncthreads();
#pragma unroll
    for (int kss = 0; kss < 2; ++kss) {
      short8 vf[8], pf[2];
#pragma unroll
      for (int nd = 0; nd < 8; ++nd)
        vf[nd] = *(const short8*)&Vs[nd * 16 + l16][kss * 32 + quad * 8];
#pragma unroll
      for (int mi = 0; mi < 2; ++mi)
        pf[mi] = *(const short8*)&Ps[wave][mi * 16 + l16][kss * 32 + quad * 8];
#pragma unroll
      for (int mi = 0; mi < 2; ++mi)
#pragma unroll
        for (int nd = 0; nd < 8; ++nd)
          acc_o[mi][nd] = __builtin_amdgcn_mfma_f32_16x16x32_bf16(pf[mi], vf[nd], acc_o[mi][nd], 0, 0, 0);
    }
    __syncthreads();
  }
#pragma unroll
  for (int mi = 0; mi < 2; ++mi)
#pragma unroll
    for (int r = 0; r < 4; ++r) {
      float inv = 1.0f / l_i[mi][r];
      int row = b * S_ + qt * 128 + wave * 32 + mi * 16 + quad * 4 + r;
#pragma unroll
      for (int nd = 0; nd < 8; ++nd)
        o[(size_t)row * D_ + h * DH_ + nd * 16 + l16] = f2bf(acc_o[mi][nd][r] * inv);
    }
}

extern "C" void kernel_launch(void* const* d_in, const int* in_sizes, int n_in,
                              void* d_out, int out_size, void* d_ws, size_t ws_size,
                              hipStream_t stream) {
  const void* hidden = d_in[0];
  const void* fcos   = d_in[1];
  const void* fsin   = d_in[2];
  const void* wq     = d_in[3];
  const void* wk     = d_in[4];
  const void* wv     = d_in[5];
  const void* wo     = d_in[6];
  const void* w1     = d_in[7];
  const void* w2     = d_in[8];
  const void* w3     = d_in[9];
  const void* anw    = d_in[10];
  const void* fnw    = d_in[11];
  const u32* probe = (const u32*)fcos;
  u16* ws  = (u16*)d_ws;

  const size_t SB = (size_t)M_ * D_;   // 8 Mi elems (16 MB)
  // Workspace layout (76 MB total): qb | vb | xb,kb (overlaid later by t1)
  u16* qb = ws;              // q, then y
  u16* vb = ws + SB;         // v, then h
  u16* xb = ws + 2 * SB;     // x, then attn-out
  u16* kb = ws + 3 * SB;     // k
  u16* t1 = ws + 2 * SB;     // FFN intermediate (22 Mi elems, overlays xb+kb)
  u16* vtb = (u16*)d_out;    // v^T parks in d_out (overwritten by final GEMM)

  dim3 gD(D_ / 128, M_ / 128);
  dim3 gF(FF_ / 128, M_ / 128);

  rmsnorm_kernel<<<M_, 256, 0, stream>>>(hidden, anw, xb, probe, 1);
  gemm_kernel<0><<<gD, 256, 0, stream>>>(xb, wq, qb, nullptr, D_, D_, probe, 0, 0);
  gemm_kernel<0><<<gD, 256, 0, stream>>>(xb, wk, kb, nullptr, D_, D_, probe, 0, 0);
  gemm_kernel<0><<<gD, 256, 0, stream>>>(xb, wv, vb, nullptr, D_, D_, probe, 0, 0);
  rope_kernel<<<(M_ * H_ * 64) / 256, 256, 0, stream>>>(qb, kb, fcos, fsin, probe);
  vtrans_kernel<<<dim3(S_ / 64, DH_ / 64, B_ * H_), 256, 0, stream>>>(vb, vtb);
  attn_kernel<<<dim3(S_ / 128, B_ * H_), 256, 0, stream>>>(qb, kb, vtb, xb);
  gemm_kernel<1><<<gD, 256, 0, stream>>>(xb, wo, vb, hidden, D_, D_, probe, 1, 0);  // h = hidden + attn@wo
  rmsnorm_kernel<<<M_, 256, 0, stream>>>(vb, fnw, qb, probe, 0);                    // y
  gemm_kernel<2><<<gF, 256, 0, stream>>>(qb, w1, t1, nullptr, FF_, D_, probe, 0, 0);// t1 = silu(y@w1)
  gemm_kernel<3><<<gF, 256, 0, stream>>>(qb, w3, t1, t1, FF_, D_, probe, 0, 0);     // t1 = (y@w3)*t1
  gemm_kernel<1><<<gD, 256, 0, stream>>>(t1, w2, d_out, vb, D_, FF_, probe, 0, 1);  // out = h + t1@w2
}

// Round 4
// 1202.159 us; speedup vs baseline: 1.1763x; 1.1763x over previous
//
#include <hip/hip_runtime.h>

#define B_ 2
#define S_ 2048
#define D_ 2048
#define H_ 16
#define DH_ 128
#define FF_ 5632
#define M_ (B_*S_)   // 4096 token rows

typedef unsigned short u16;
typedef unsigned int u32;
typedef __attribute__((ext_vector_type(8))) short short8;   // 8 bf16 (4 VGPRs)
typedef __attribute__((ext_vector_type(4))) float floatx4;  // MFMA C/D

__device__ __forceinline__ float bf2f(u16 h) {
  union { u32 u; float f; } v; v.u = ((u32)h) << 16; return v.f;
}
__device__ __forceinline__ u16 f2bf(float f) {
  union { float f; u32 u; } v; v.f = f;
  u32 u = v.u;
  return (u16)((u + 0x7FFFu + ((u >> 16) & 1u)) >> 16);
}
__device__ __forceinline__ bool probe_f32(const u32* p) { return (p[0] & 0xFFFFu) == 0u; }

// async global->LDS, 16B per lane; LDS dest = wave-uniform base + lane*16
__device__ __forceinline__ void gl_lds16(const void* g, void* l) {
  __builtin_amdgcn_global_load_lds((const __attribute__((address_space(1))) void*)g,
                                   (__attribute__((address_space(3))) void*)l, 16, 0, 0);
}

// ---------------- RMSNorm: one block per row of 2048 ----------------
__global__ __launch_bounds__(256) void rmsnorm_kernel(
    const void* __restrict__ x, const void* __restrict__ w, u16* __restrict__ o,
    const u32* __restrict__ probe, int x_ext) {
  const bool m = probe_f32(probe);
  const bool xf = m && (x_ext != 0);
  const int row = blockIdx.x;
  const int tid = threadIdx.x;
  float v[8];
  if (xf) {
    const float* xr = (const float*)x + (size_t)row * D_;
    float4 p0 = *(const float4*)(xr + tid * 8);
    float4 p1 = *(const float4*)(xr + tid * 8 + 4);
    v[0]=p0.x; v[1]=p0.y; v[2]=p0.z; v[3]=p0.w;
    v[4]=p1.x; v[5]=p1.y; v[6]=p1.z; v[7]=p1.w;
  } else {
    const u16* xr = (const u16*)x + (size_t)row * D_;
    uint4 p = *(const uint4*)(xr + tid * 8);
    u32 ua[4] = {p.x, p.y, p.z, p.w};
#pragma unroll
    for (int i = 0; i < 4; ++i) {
      v[2*i]   = bf2f((u16)(ua[i] & 0xffffu));
      v[2*i+1] = bf2f((u16)(ua[i] >> 16));
    }
  }
  float ss = 0.f;
#pragma unroll
  for (int i = 0; i < 8; ++i) ss += v[i] * v[i];
#pragma unroll
  for (int d = 1; d < 64; d <<= 1) ss += __shfl_xor(ss, d);
  __shared__ float sbuf[4];
  if ((tid & 63) == 0) sbuf[tid >> 6] = ss;
  __syncthreads();
  float tot = sbuf[0] + sbuf[1] + sbuf[2] + sbuf[3];
  float sc = rsqrtf(tot * (1.0f / (float)D_) + 1e-6f);
  float wv[8];
  if (m) {
    const float* wr = (const float*)w;
    float4 p0 = *(const float4*)(wr + tid * 8);
    float4 p1 = *(const float4*)(wr + tid * 8 + 4);
    wv[0]=p0.x; wv[1]=p0.y; wv[2]=p0.z; wv[3]=p0.w;
    wv[4]=p1.x; wv[5]=p1.y; wv[6]=p1.z; wv[7]=p1.w;
  } else {
    uint4 pw = *(const uint4*)((const u16*)w + tid * 8);
    u32 uw[4] = {pw.x, pw.y, pw.z, pw.w};
#pragma unroll
    for (int i = 0; i < 4; ++i) {
      wv[2*i]   = bf2f((u16)(uw[i] & 0xffffu));
      wv[2*i+1] = bf2f((u16)(uw[i] >> 16));
    }
  }
  u32 ow[4];
#pragma unroll
  for (int i = 0; i < 4; ++i) {
    float n0 = v[2*i] * sc, n1 = v[2*i+1] * sc;
    if (!m) { n0 = bf2f(f2bf(n0)); n1 = bf2f(f2bf(n1)); }
    n0 *= wv[2*i]; n1 *= wv[2*i+1];
    ow[i] = (u32)f2bf(n0) | ((u32)f2bf(n1) << 16);
  }
  uint4 po; po.x = ow[0]; po.y = ow[1]; po.z = ow[2]; po.w = ow[3];
  *(uint4*)(o + (size_t)row * D_ + tid * 8) = po;
}

// ---------------- weight transpose-convert: W[K][N] f32 -> WT[N][K] bf16 ----------------
__global__ __launch_bounds__(256) void wtrans_kernel(
    const float* __restrict__ W, u16* __restrict__ WT, int Kdim, int Ndim) {
  __shared__ u16 tl[64][72];
  const int n0 = blockIdx.x * 64, k0 = blockIdx.y * 64;
  const int tid = threadIdx.x;
#pragma unroll
  for (int i = 0; i < 4; ++i) {
    int c = tid + i * 256;          // 1024 float4 slots
    int kr = c >> 4, nc = (c & 15) * 4;
    float4 v = *(const float4*)(W + (size_t)(k0 + kr) * Ndim + n0 + nc);
    uint2 p;
    p.x = (u32)f2bf(v.x) | ((u32)f2bf(v.y) << 16);
    p.y = (u32)f2bf(v.z) | ((u32)f2bf(v.w) << 16);
    *(uint2*)&tl[kr][nc] = p;       // 8B aligned: row stride 144B, nc*2 mult of 8
  }
  __syncthreads();
#pragma unroll
  for (int i = 0; i < 2; ++i) {
    int c = tid + i * 256;          // 512 chunks of 8
    int nr = c >> 3, kc = (c & 7) * 8;
    u16 t[8];
#pragma unroll
    for (int j = 0; j < 8; ++j) t[j] = tl[kc + j][nr];
    uint4 w0;
    w0.x = (u32)t[0] | ((u32)t[1] << 16); w0.y = (u32)t[2] | ((u32)t[3] << 16);
    w0.z = (u32)t[4] | ((u32)t[5] << 16); w0.w = (u32)t[6] | ((u32)t[7] << 16);
    *(uint4*)(WT + (size_t)(n0 + nr) * Kdim + k0 + kc) = w0;
  }
}

// ---------------- fast GEMM (m97 structure): C[M,N] = A[M,K] @ BT[N][K]^T ----------------
// 128x128 tile, BK=32, 4 waves, wave tile 64x64; both operands staged via global_load_lds x16.
// EPI: 0 plain | 1 C=acc+Res | 2 C=silu(acc) | 3 C=acc*Res (Res aliases C, internal bf16)
template<int EPI>
__global__ __launch_bounds__(256) void gemm_bt_kernel(
    const u16* __restrict__ A, const u16* __restrict__ BT,
    void* C, const void* Res, int Ndim, int Kdim, int res_f32, int c_f32) {
  __shared__ u16 As[128 * 32];   // [m][k], unpadded (global_load_lds needs contiguity)
  __shared__ u16 Bs[128 * 32];   // [n][k]
  const int tid = threadIdx.x;
  const int wave = tid >> 6, lane = tid & 63;
  const int quad = lane >> 4, l16 = lane & 15;
  const int waveM = wave & 1, waveN = wave >> 1;
  const int mb = blockIdx.y * 128, nb = blockIdx.x * 128;

  // staging: each wave fills 2 chunks of 16 rows (1024B) per operand
  const int srow = wave * 32 + (lane >> 2);
  const int skof = (lane & 3) * 8;
  const u16* aP0 = A  + (size_t)(mb + srow) * Kdim + skof;
  const u16* aP1 = aP0 + (size_t)16 * Kdim;
  const u16* bP0 = BT + (size_t)(nb + srow) * Kdim + skof;
  const u16* bP1 = bP0 + (size_t)16 * Kdim;
  u16* lA0 = As + (wave * 2)     * 512;
  u16* lA1 = As + (wave * 2 + 1) * 512;
  u16* lB0 = Bs + (wave * 2)     * 512;
  u16* lB1 = Bs + (wave * 2 + 1) * 512;

  floatx4 acc[4][4];
#pragma unroll
  for (int i = 0; i < 4; ++i)
#pragma unroll
    for (int j = 0; j < 4; ++j) { floatx4 z = {0.f,0.f,0.f,0.f}; acc[i][j] = z; }

  const int kTiles = Kdim >> 5;
  for (int kt = 0; kt < kTiles; ++kt) {
    gl_lds16(aP0, lA0); gl_lds16(aP1, lA1);
    gl_lds16(bP0, lB0); gl_lds16(bP1, lB1);
    aP0 += 32; aP1 += 32; bP0 += 32; bP1 += 32;
    __syncthreads();   // drains vmcnt (global_load_lds) per barrier semantics
    short8 af[4], bfr[4];
#pragma unroll
    for (int i = 0; i < 4; ++i)
      af[i] = *(const short8*)&As[(size_t)(waveM * 64 + i * 16 + l16) * 32 + quad * 8];
#pragma unroll
    for (int i = 0; i < 4; ++i)
      bfr[i] = *(const short8*)&Bs[(size_t)(waveN * 64 + i * 16 + l16) * 32 + quad * 8];
#pragma unroll
    for (int mi = 0; mi < 4; ++mi)
#pragma unroll
      for (int ni = 0; ni < 4; ++ni)
        acc[mi][ni] = __builtin_amdgcn_mfma_f32_16x16x32_bf16(af[mi], bfr[ni], acc[mi][ni], 0, 0, 0);
    __syncthreads();
  }
  // epilogue: D layout row = quad*4+r, col = l16
#pragma unroll
  for (int mi = 0; mi < 4; ++mi)
#pragma unroll
    for (int ni = 0; ni < 4; ++ni) {
      int gm0 = mb + waveM * 64 + mi * 16 + quad * 4;
      int gn  = nb + waveN * 64 + ni * 16 + l16;
#pragma unroll
      for (int r = 0; r < 4; ++r) {
        float v = acc[mi][ni][r];
        size_t idx = (size_t)(gm0 + r) * Ndim + gn;
        if (EPI == 1) v += res_f32 ? ((const float*)Res)[idx] : bf2f(((const u16*)Res)[idx]);
        if (EPI == 2) v = v / (1.f + __expf(-v));
        if (EPI == 3) v *= bf2f(((const u16*)Res)[idx]);
        if (c_f32) ((float*)C)[idx] = v;
        else       ((u16*)C)[idx] = f2bf(v);
      }
    }
}

// ---------------- fallback GEMM (round-3 proven): dual-dtype scalar B staging ----------------
template<int EPI>
__global__ __launch_bounds__(256, 2) void gemm_kernel(
    const u16* __restrict__ A, const void* __restrict__ Bm,
    void* C, const void* Res,
    int Ndim, int Kdim, const u32* __restrict__ probe, int res_ext, int c_ext) {
  const bool m = probe_f32(probe);
  const bool rf = m && (res_ext != 0);
  const bool cf = m && (c_ext != 0);
  __shared__ u16 As[128][40];
  __shared__ u16 Bs[128][40];
  const int tid = threadIdx.x;
  const int wave = tid >> 6, lane = tid & 63;
  const int quad = lane >> 4, l16 = lane & 15;
  const int waveM = wave & 1, waveN = wave >> 1;
  const int mb = blockIdx.y * 128, nb = blockIdx.x * 128;

  floatx4 acc[4][4];
#pragma unroll
  for (int i = 0; i < 4; ++i)
#pragma unroll
    for (int j = 0; j < 4; ++j) { floatx4 z = {0.f,0.f,0.f,0.f}; acc[i][j] = z; }

  const int kTiles = Kdim >> 5;
  for (int kt = 0; kt < kTiles; ++kt) {
    const int k0 = kt << 5;
#pragma unroll
    for (int i = 0; i < 2; ++i) {
      int c = tid + i * 256;
      int row = c >> 2, kc = (c & 3) << 3;
      uint4 val = *(const uint4*)(A + (size_t)(mb + row) * Kdim + k0 + kc);
      *(uint4*)&As[row][kc] = val;
    }
    {
      int n = tid & 127, kh = tid >> 7;
      u16 t[16];
      if (m) {
        const float* Bf = (const float*)Bm;
#pragma unroll
        for (int j = 0; j < 16; ++j)
          t[j] = f2bf(Bf[(size_t)(k0 + kh * 16 + j) * Ndim + nb + n]);
      } else {
        const u16* Bh = (const u16*)Bm;
#pragma unroll
        for (int j = 0; j < 16; ++j)
          t[j] = Bh[(size_t)(k0 + kh * 16 + j) * Ndim + nb + n];
      }
      uint4 w0, w1;
      w0.x = (u32)t[0] | ((u32)t[1] << 16);   w0.y = (u32)t[2] | ((u32)t[3] << 16);
      w0.z = (u32)t[4] | ((u32)t[5] << 16);   w0.w = (u32)t[6] | ((u32)t[7] << 16);
      w1.x = (u32)t[8] | ((u32)t[9] << 16);   w1.y = (u32)t[10] | ((u32)t[11] << 16);
      w1.z = (u32)t[12] | ((u32)t[13] << 16); w1.w = (u32)t[14] | ((u32)t[15] << 16);
      *(uint4*)&Bs[n][kh * 16]     = w0;
      *(uint4*)&Bs[n][kh * 16 + 8] = w1;
    }
    __syncthreads();
    short8 af[4], bfr[4];
#pragma unroll
    for (int i = 0; i < 4; ++i)
      af[i] = *(const short8*)&As[waveM * 64 + i * 16 + l16][quad * 8];
#pragma unroll
    for (int i = 0; i < 4; ++i)
      bfr[i] = *(const short8*)&Bs[waveN * 64 + i * 16 + l16][quad * 8];
#pragma unroll
    for (int mi = 0; mi < 4; ++mi)
#pragma unroll
      for (int ni = 0; ni < 4; ++ni)
        acc[mi][ni] = __builtin_amdgcn_mfma_f32_16x16x32_bf16(af[mi], bfr[ni], acc[mi][ni], 0, 0, 0);
    __syncthreads();
  }
#pragma unroll
  for (int mi = 0; mi < 4; ++mi)
#pragma unroll
    for (int ni = 0; ni < 4; ++ni) {
      int gm0 = mb + waveM * 64 + mi * 16 + quad * 4;
      int gn  = nb + waveN * 64 + ni * 16 + l16;
#pragma unroll
      for (int r = 0; r < 4; ++r) {
        float v = acc[mi][ni][r];
        size_t idx = (size_t)(gm0 + r) * Ndim + gn;
        if (EPI == 1) v += rf ? ((const float*)Res)[idx] : bf2f(((const u16*)Res)[idx]);
        if (EPI == 2) v = v / (1.f + __expf(-v));
        if (EPI == 3) v *= bf2f(((const u16*)Res)[idx]);
        if (cf) ((float*)C)[idx] = v;
        else    ((u16*)C)[idx] = f2bf(v);
      }
    }
}

// ---------------- RoPE on q and k in-place ----------------
__global__ __launch_bounds__(256) void rope_kernel(
    u16* __restrict__ q, u16* __restrict__ k,
    const void* __restrict__ ct, const void* __restrict__ st,
    const u32* __restrict__ probe) {
  const bool m = probe_f32(probe);
  int idx = blockIdx.x * 256 + threadIdx.x;
  int row = idx >> 10;
  int rem = idx & 1023;
  int h = rem >> 6, j = rem & 63;
  int s = row & (S_ - 1);
  size_t a = (size_t)row * D_ + h * DH_ + 2 * j;
  float c, sn;
  if (m) { c = ((const float*)ct)[s * 64 + j]; sn = ((const float*)st)[s * 64 + j]; }
  else   { c = bf2f(((const u16*)ct)[s * 64 + j]); sn = bf2f(((const u16*)st)[s * 64 + j]); }
  u32 qq = *(u32*)(q + a);
  float xr = bf2f((u16)(qq & 0xffffu)), xi = bf2f((u16)(qq >> 16));
  *(u32*)(q + a) = (u32)f2bf(xr * c - xi * sn) | ((u32)f2bf(xr * sn + xi * c) << 16);
  u32 kk = *(u32*)(k + a);
  xr = bf2f((u16)(kk & 0xffffu)); xi = bf2f((u16)(kk >> 16));
  *(u32*)(k + a) = (u32)f2bf(xr * c - xi * sn) | ((u32)f2bf(xr * sn + xi * c) << 16);
}

// ---------------- V transpose: (b,s,h,d) -> (b,h,d,s) ----------------
__global__ __launch_bounds__(256) void vtrans_kernel(
    const u16* __restrict__ v, u16* __restrict__ vt) {
  __shared__ u16 tl[64][72];
  int s0 = blockIdx.x * 64, d0 = blockIdx.y * 64;
  int bh = blockIdx.z, b = bh >> 4, h = bh & 15;
  int tid = threadIdx.x;
#pragma unroll
  for (int i = 0; i < 2; ++i) {
    int c = tid + i * 256;
    int row = c >> 3, dc = (c & 7) << 3;
    uint4 val = *(const uint4*)(v + (size_t)(b * S_ + s0 + row) * D_ + h * DH_ + d0 + dc);
    *(uint4*)&tl[row][dc] = val;
  }
  __syncthreads();
#pragma unroll
  for (int i = 0; i < 2; ++i) {
    int c = tid + i * 256;
    int dr = c >> 3, sc = (c & 7) << 3;
    u16 t[8];
#pragma unroll
    for (int j = 0; j < 8; ++j) t[j] = tl[sc + j][dr];
    uint4 w0;
    w0.x = (u32)t[0] | ((u32)t[1] << 16); w0.y = (u32)t[2] | ((u32)t[3] << 16);
    w0.z = (u32)t[4] | ((u32)t[5] << 16); w0.w = (u32)t[6] | ((u32)t[7] << 16);
    *(uint4*)(vt + (size_t)(bh * DH_ + d0 + dr) * S_ + s0 + sc) = w0;
  }
}

// ---------------- Flash attention (causal), Q-tile 128, K-tile 64 ----------------
__global__ __launch_bounds__(256, 1) void attn_kernel(
    const u16* __restrict__ q, const u16* __restrict__ k,
    const u16* __restrict__ vt, u16* __restrict__ o) {
  __shared__ u16 Ks[64][136];
  __shared__ u16 Vs[128][72];
  __shared__ u16 Ps[4][32][72];
  const int qt = blockIdx.x, bh = blockIdx.y;
  const int b = bh >> 4, h = bh & 15;
  const int tid = threadIdx.x;
  const int wave = tid >> 6, lane = tid & 63;
  const int quad = lane >> 4, l16 = lane & 15;

  short8 qa[2][4];
  const u16* qbase = q + (size_t)(b * S_ + qt * 128 + wave * 32) * D_ + h * DH_;
#pragma unroll
  for (int mi = 0; mi < 2; ++mi)
#pragma unroll
    for (int ks = 0; ks < 4; ++ks)
      qa[mi][ks] = *(const short8*)(qbase + (size_t)(mi * 16 + l16) * D_ + ks * 32 + quad * 8);

  float m_i[2][4], l_i[2][4];
  floatx4 acc_o[2][8];
#pragma unroll
  for (int mi = 0; mi < 2; ++mi) {
#pragma unroll
    for (int r = 0; r < 4; ++r) { m_i[mi][r] = -1e30f; l_i[mi][r] = 0.f; }
#pragma unroll
    for (int nd = 0; nd < 8; ++nd) { floatx4 z = {0.f,0.f,0.f,0.f}; acc_o[mi][nd] = z; }
  }

  const int nkt = 2 * qt + 2;
  for (int kt = 0; kt < nkt; ++kt) {
#pragma unroll
    for (int i = 0; i < 4; ++i) {
      int c = tid + i * 256;
      int row = c >> 4, dc = (c & 15) << 3;
      uint4 val = *(const uint4*)(k + (size_t)(b * S_ + kt * 64 + row) * D_ + h * DH_ + dc);
      *(uint4*)&Ks[row][dc] = val;
    }
#pragma unroll
    for (int i = 0; i < 4; ++i) {
      int c = tid + i * 256;
      int row = c >> 3, sc = (c & 7) << 3;
      uint4 val = *(const uint4*)(vt + (size_t)(bh * DH_ + row) * S_ + kt * 64 + sc);
      *(uint4*)&Vs[row][sc] = val;
    }
    __syncthreads();

    floatx4 accs[2][4];
#pragma unroll
    for (int mi = 0; mi < 2; ++mi)
#pragma unroll
      for (int ni = 0; ni < 4; ++ni) { floatx4 z = {0.f,0.f,0.f,0.f}; accs[mi][ni] = z; }
#pragma unroll
    for (int ks = 0; ks < 4; ++ks) {
      short8 kf[4];
#pragma unroll
      for (int ni = 0; ni < 4; ++ni)
        kf[ni] = *(const short8*)&Ks[ni * 16 + l16][ks * 32 + quad * 8];
#pragma unroll
      for (int mi = 0; mi < 2; ++mi)
#pragma unroll
        for (int ni = 0; ni < 4; ++ni)
          accs[mi][ni] = __builtin_amdgcn_mfma_f32_16x16x32_bf16(qa[mi][ks], kf[ni], accs[mi][ni], 0, 0, 0);
    }

    const float scl = 0.08838834764831845f;
    const bool diag = (kt >= 2 * qt);
#pragma unroll
    for (int mi = 0; mi < 2; ++mi) {
#pragma unroll
      for (int r = 0; r < 4; ++r) {
        int qg = qt * 128 + wave * 32 + mi * 16 + quad * 4 + r;
        float mx = -1e30f;
#pragma unroll
        for (int ni = 0; ni < 4; ++ni) {
          float sv = accs[mi][ni][r] * scl;
          int kg = kt * 64 + ni * 16 + l16;
          if (diag && kg > qg) sv = -1e30f;
          accs[mi][ni][r] = sv;
          mx = fmaxf(mx, sv);
        }
#pragma unroll
        for (int d = 1; d < 16; d <<= 1) mx = fmaxf(mx, __shfl_xor(mx, d));
        float mn = fmaxf(m_i[mi][r], mx);
        float al = __expf(m_i[mi][r] - mn);
        float rs = 0.f;
#pragma unroll
        for (int ni = 0; ni < 4; ++ni) {
          float p = __expf(accs[mi][ni][r] - mn);
          accs[mi][ni][r] = p;
          rs += p;
        }
#pragma unroll
        for (int d = 1; d < 16; d <<= 1) rs += __shfl_xor(rs, d);
        l_i[mi][r] = l_i[mi][r] * al + rs;
        m_i[mi][r] = mn;
#pragma unroll
        for (int nd = 0; nd < 8; ++nd) acc_o[mi][nd][r] *= al;
      }
    }
#pragma unroll
    for (int mi = 0; mi < 2; ++mi)
#pragma unroll
      for (int ni = 0; ni < 4; ++ni)
#pragma unroll
        for (int r = 0; r < 4; ++r)
          Ps[wave][mi * 16 + quad * 4 + r][ni * 16 + l16] = f2bf(accs[mi][ni][r]);
    __syncthreads();
#pragma unroll
    for (int kss = 0; kss < 2; ++kss) {
      short8 vf[8], pf[2];
#pragma unroll
      for (int nd = 0; nd < 8; ++nd)
        vf[nd] = *(const short8*)&Vs[nd * 16 + l16][kss * 32 + quad * 8];
#pragma unroll
      for (int mi = 0; mi < 2; ++mi)
        pf[mi] = *(const short8*)&Ps[wave][mi * 16 + l16][kss * 32 + quad * 8];
#pragma unroll
      for (int mi = 0; mi < 2; ++mi)
#pragma unroll
        for (int nd = 0; nd < 8; ++nd)
          acc_o[mi][nd] = __builtin_amdgcn_mfma_f32_16x16x32_bf16(pf[mi], vf[nd], acc_o[mi][nd], 0, 0, 0);
    }
    __syncthreads();
  }
#pragma unroll
  for (int mi = 0; mi < 2; ++mi)
#pragma unroll
    for (int r = 0; r < 4; ++r) {
      float inv = 1.0f / l_i[mi][r];
      int row = b * S_ + qt * 128 + wave * 32 + mi * 16 + quad * 4 + r;
#pragma unroll
      for (int nd = 0; nd < 8; ++nd)
        o[(size_t)row * D_ + h * DH_ + nd * 16 + l16] = f2bf(acc_o[mi][nd][r] * inv);
    }
}

extern "C" void kernel_launch(void* const* d_in, const int* in_sizes, int n_in,
                              void* d_out, int out_size, void* d_ws, size_t ws_size,
                              hipStream_t stream) {
  const void* hidden = d_in[0];
  const void* fcos   = d_in[1];
  const void* fsin   = d_in[2];
  const void* wq     = d_in[3];
  const void* wk     = d_in[4];
  const void* wv     = d_in[5];
  const void* wo     = d_in[6];
  const void* w1     = d_in[7];
  const void* w2     = d_in[8];
  const void* w3     = d_in[9];
  const void* anw    = d_in[10];
  const void* fnw    = d_in[11];
  const u32* probe = (const u32*)fcos;
  u16* ws  = (u16*)d_ws;

  const size_t SB = (size_t)M_ * D_;    // 8 Mi elems (16 MB)
  const size_t FB = (size_t)M_ * FF_;   // 22 Mi elems (44 MB)
  const size_t DD = (size_t)D_ * D_;    // 4 Mi elems
  const size_t DF = (size_t)D_ * FF_;   // 11 Mi elems
  u16* qb = ws;              // q, then y
  u16* vb = ws + SB;         // v, then h
  u16* xb = ws + 2 * SB;     // x, then attn-out
  u16* kb = ws + 3 * SB;     // k
  u16* t1 = ws + 2 * SB;     // FFN intermediate (overlays xb+kb)
  u16* vtb = (u16*)d_out;    // v^T parks in d_out

  const size_t baseElems = 2 * SB + FB;               // 38 Mi elems
  const size_t wElems = 4 * DD + 3 * DF;              // 51.4 M elems
  const bool fast = ws_size >= (baseElems + wElems) * sizeof(u16);

  dim3 gD(D_ / 128, M_ / 128);
  dim3 gF(FF_ / 128, M_ / 128);

  if (fast) {
    u16* wqT = ws + baseElems;
    u16* wkT = wqT + DD;
    u16* wvT = wkT + DD;
    u16* woT = wvT + DD;
    u16* w1T = woT + DD;   // [FF][D]
    u16* w3T = w1T + DF;   // [FF][D]
    u16* w2T = w3T + DF;   // [D][FF]
    wtrans_kernel<<<dim3(D_/64,  D_/64),  256, 0, stream>>>((const float*)wq, wqT, D_, D_);
    wtrans_kernel<<<dim3(D_/64,  D_/64),  256, 0, stream>>>((const float*)wk, wkT, D_, D_);
    wtrans_kernel<<<dim3(D_/64,  D_/64),  256, 0, stream>>>((const float*)wv, wvT, D_, D_);
    wtrans_kernel<<<dim3(D_/64,  D_/64),  256, 0, stream>>>((const float*)wo, woT, D_, D_);
    wtrans_kernel<<<dim3(FF_/64, D_/64),  256, 0, stream>>>((const float*)w1, w1T, D_, FF_);
    wtrans_kernel<<<dim3(FF_/64, D_/64),  256, 0, stream>>>((const float*)w3, w3T, D_, FF_);
    wtrans_kernel<<<dim3(D_/64,  FF_/64), 256, 0, stream>>>((const float*)w2, w2T, FF_, D_);

    rmsnorm_kernel<<<M_, 256, 0, stream>>>(hidden, anw, xb, probe, 1);
    gemm_bt_kernel<0><<<gD, 256, 0, stream>>>(xb, wqT, qb, nullptr, D_, D_, 0, 0);
    gemm_bt_kernel<0><<<gD, 256, 0, stream>>>(xb, wkT, kb, nullptr, D_, D_, 0, 0);
    gemm_bt_kernel<0><<<gD, 256, 0, stream>>>(xb, wvT, vb, nullptr, D_, D_, 0, 0);
    rope_kernel<<<(M_ * H_ * 64) / 256, 256, 0, stream>>>(qb, kb, fcos, fsin, probe);
    vtrans_kernel<<<dim3(S_ / 64, DH_ / 64, B_ * H_), 256, 0, stream>>>(vb, vtb);
    attn_kernel<<<dim3(S_ / 128, B_ * H_), 256, 0, stream>>>(qb, kb, vtb, xb);
    gemm_bt_kernel<1><<<gD, 256, 0, stream>>>(xb, woT, vb, hidden, D_, D_, 1, 0);
    rmsnorm_kernel<<<M_, 256, 0, stream>>>(vb, fnw, qb, probe, 0);
    gemm_bt_kernel<2><<<gF, 256, 0, stream>>>(qb, w1T, t1, nullptr, FF_, D_, 0, 0);
    gemm_bt_kernel<3><<<gF, 256, 0, stream>>>(qb, w3T, t1, t1, FF_, D_, 0, 0);
    gemm_bt_kernel<1><<<gD, 256, 0, stream>>>(t1, w2T, d_out, vb, D_, FF_, 0, 1);
  } else {
    rmsnorm_kernel<<<M_, 256, 0, stream>>>(hidden, anw, xb, probe, 1);
    gemm_kernel<0><<<gD, 256, 0, stream>>>(xb, wq, qb, nullptr, D_, D_, probe, 0, 0);
    gemm_kernel<0><<<gD, 256, 0, stream>>>(xb, wk, kb, nullptr, D_, D_, probe, 0, 0);
    gemm_kernel<0><<<gD, 256, 0, stream>>>(xb, wv, vb, nullptr, D_, D_, probe, 0, 0);
    rope_kernel<<<(M_ * H_ * 64) / 256, 256, 0, stream>>>(qb, kb, fcos, fsin, probe);
    vtrans_kernel<<<dim3(S_ / 64, DH_ / 64, B_ * H_), 256, 0, stream>>>(vb, vtb);
    attn_kernel<<<dim3(S_ / 128, B_ * H_), 256, 0, stream>>>(qb, kb, vtb, xb);
    gemm_kernel<1><<<gD, 256, 0, stream>>>(xb, wo, vb, hidden, D_, D_, probe, 1, 0);
    rmsnorm_kernel<<<M_, 256, 0, stream>>>(vb, fnw, qb, probe, 0);
    gemm_kernel<2><<<gF, 256, 0, stream>>>(qb, w1, t1, nullptr, FF_, D_, probe, 0, 0);
    gemm_kernel<3><<<gF, 256, 0, stream>>>(qb, w3, t1, t1, FF_, D_, probe, 0, 0);
    gemm_kernel<1><<<gD, 256, 0, stream>>>(t1, w2, d_out, vb, D_, FF_, probe, 0, 1);
  }
}